// Round 5
// baseline (15.115 us; speedup 1.0000x reference)
//
#include <hip/hip_runtime.h>
#include <math.h>

typedef _Float16 half8 __attribute__((ext_vector_type(8)));
typedef _Float16 half4 __attribute__((ext_vector_type(4)));
typedef float f32x4 __attribute__((ext_vector_type(4)));

#define NN 1024
#define DD 256

// ---------------------------------------------------------------------------
// Kernel 1: prep — one pass over pred (f32, coalesced):
//   * row norms ||pred[row]||^2 in exact f32 via wave shuffle-reduce -> norms
//   * f16 copy pre-swizzled to fragment order: p16[[chunk c=k>>3][row][8 f16]]
//     so a GEMM fragment load is ONE dwordx4, 16 consecutive lanes contiguous.
// 256 blocks x 256 thr, one row per wave.
// ---------------------------------------------------------------------------
__global__ __launch_bounds__(256) void prep_k(const float* __restrict__ pred,
                                              _Float16* __restrict__ p16,
                                              float* __restrict__ norms) {
    const int w = threadIdx.x >> 6;
    const int lane = threadIdx.x & 63;
    const int row = (blockIdx.x << 2) + w;

    const float4 v = *reinterpret_cast<const float4*>(pred + (size_t)row * DD + (lane << 2));

    float s = v.x * v.x + v.y * v.y + v.z * v.z + v.w * v.w;
    #pragma unroll
    for (int off = 32; off >= 1; off >>= 1) s += __shfl_xor(s, off, 64);
    if (lane == 0) norms[row] = s;

    half4 h;
    h[0] = (_Float16)v.x; h[1] = (_Float16)v.y;
    h[2] = (_Float16)v.z; h[3] = (_Float16)v.w;
    const int c = lane >> 1;            // k-chunk = (4*lane)>>3
    const int j = (lane & 1) << 2;      // low/high half of the 8-f16 slot
    *reinterpret_cast<half4*>(p16 + ((((size_t)c << 10) + row) << 3) + j) = h;
}

// ---------------------------------------------------------------------------
// Kernel 2: 32x32 output tile per block, grid 32x32 = 1024 blocks (= exactly
// 4 blocks/CU x 256 CUs -> whole grid co-resident), 4 waves/block, each wave
// one 16x16 quadrant with full K=256. No LDS/syncthreads. Per wave: 16 frag
// loads + 8 MFMA (norm MFMAs removed -> 2/3 less MFMA issue vs R4) + float4
// epilogue. Norms read from ws (L2-hit): scalar per-row + broadcast float4.
// ---------------------------------------------------------------------------
__global__ __launch_bounds__(256, 4) void pdist_k(const _Float16* __restrict__ p16,
                                                  const float* __restrict__ ytrue,
                                                  const float* __restrict__ norms,
                                                  float* __restrict__ out) {
    const int bi = blockIdx.y, bj = blockIdx.x;
    const int i0 = bi << 5, j0 = bj << 5;
    const int tid = threadIdx.x;

    if (bj < bi) {                    // entirely below diagonal -> zeros
        const int r = tid >> 3, c4 = tid & 7;   // 256 float4 slots = 32x32
        *reinterpret_cast<float4*>(out + (size_t)(i0 + r) * NN + j0 + (c4 << 2)) =
            make_float4(0.f, 0.f, 0.f, 0.f);
        return;
    }

    const int w = tid >> 6;           // wave 0..3 -> 2x2 quadrants of 16x16
    const int lane = tid & 63;
    const int l16 = lane & 15;
    const int lq = lane >> 4;
    const int rq = lq << 2;
    const int wr = w >> 1, wc = w & 1;

    const int row = i0 + (wr << 4) + l16;    // this lane's output row
    const int col0 = j0 + (wc << 4) + rq;    // first of its 4 output cols
    const int brow = j0 + (wc << 4) + l16;   // B-fragment source row (a col)

    // Prefetches — latencies hide under the k-loop
    const float4 t4 = *reinterpret_cast<const float4*>(ytrue + (size_t)row * NN + col0);
    const float nrow = norms[row];
    const float4 nc4 = *reinterpret_cast<const float4*>(norms + col0);

    f32x4 acc = {};
    #pragma unroll
    for (int ks = 0; ks < 8; ++ks) {  // K = 256 = 8 chunks of 32
        const int c = (ks << 2) + lq;
        const size_t cb = (size_t)c << 13;    // c * 1024 rows * 8 f16
        const half8 fa = *reinterpret_cast<const half8*>(p16 + cb + ((size_t)row << 3));
        const half8 fb = *reinterpret_cast<const half8*>(p16 + cb + ((size_t)brow << 3));
        acc = __builtin_amdgcn_mfma_f32_16x16x32_f16(fb, fa, acc, 0, 0, 0);
    }

    // acc[v] = Gram[row][col0+v] (transposed orientation: lane holds 4 cols)
    const float* pn = &nc4.x;
    const float* pt = &t4.x;
    float4 o;
    float* po = &o.x;
    #pragma unroll
    for (int v = 0; v < 4; ++v) {
        const int col = col0 + v;
        const float d2 = nrow + pn[v] - 2.0f * acc[v];
        const float val = (row == col || d2 <= 0.f) ? 0.f : sqrtf(d2);
        const float diff = val - pt[v];
        po[v] = (col >= row) ? diff * diff : 0.f;
    }
    *reinterpret_cast<float4*>(out + (size_t)row * NN + col0) = o;
}

extern "C" void kernel_launch(void* const* d_in, const int* in_sizes, int n_in,
                              void* d_out, int out_size, void* d_ws, size_t ws_size,
                              hipStream_t stream) {
    const float* y_true = (const float*)d_in[0];   // (1024, 1024)
    const float* y_pred = (const float*)d_in[1];   // (1024, 256)
    float* out = (float*)d_out;

    _Float16* p16 = (_Float16*)d_ws;                       // 512 KB swizzled f16 pred
    float* norms = (float*)((char*)d_ws + (size_t)NN * DD * 2);  // 4 KB norms

    hipLaunchKernelGGL(prep_k, dim3(NN / 4), dim3(256), 0, stream, y_pred, p16, norms);
    hipLaunchKernelGGL(pdist_k, dim3(32, 32), dim3(256), 0, stream,
                       p16, y_true, norms, out);
}